// Round 1
// baseline (805.910 us; speedup 1.0000x reference)
//
#include <hip/hip_runtime.h>
#include <hip/hip_bf16.h>

// MMD (InfoVAE RBF-kernel) on MI355X.
// N=8192, D=128, fp32 in, single fp32 scalar out.
//
// Numerics: true MMD ~3.6e-6 while each kernel-mean ~0.985 (cancellation to
// ~4e-6 relative), threshold 7.15e-8 absolute -> per-thread/block/global
// accumulation MUST be fp64. Per-element work stays fp32 (expf rounding is
// zero-mean-ish and its bias cancels across the +1/+1/-2 combination).

#define NN 8192
#define DD 128

constexpr int BM = 128, BN = 128, BK = 32;
constexpr int TM = 8, TN = 8;
constexpr int THREADS = 256;           // 16x16 thread layout, 8x8 per thread
constexpr int LDA = BM + 4;            // 132: keeps 16B alignment for float4 LDS reads

__global__ __launch_bounds__(THREADS) void mmd_pairsum(
    const float* __restrict__ X,       // true_samples (x)
    const float* __restrict__ Y,       // inputs (y)
    double* __restrict__ sums) {
  const int mode = blockIdx.z;         // 0: xx, 1: yy, 2: xy
  const float* __restrict__ A = (mode == 1) ? Y : X;
  const float* __restrict__ B = (mode == 0) ? X : Y;
  const int bi = blockIdx.y * BM;
  const int bj = blockIdx.x * BN;

  __shared__ float As[BK][LDA];
  __shared__ float Bs[BK][LDA];
  __shared__ double red[THREADS];

  const int tid = threadIdx.x;
  const int tx = tid & 15;             // col group (B side)
  const int ty = tid >> 4;             // row group (A side)

  float acc[TM][TN];
#pragma unroll
  for (int i = 0; i < TM; ++i)
#pragma unroll
    for (int j = 0; j < TN; ++j) acc[i][j] = 0.f;
  float a2[TM];
  float b2[TN];
#pragma unroll
  for (int i = 0; i < TM; ++i) a2[i] = 0.f;
#pragma unroll
  for (int j = 0; j < TN; ++j) b2[j] = 0.f;

  for (int kt = 0; kt < DD; kt += BK) {
    // Stage 128x32 tiles of A and B, transposed into LDS ([k][m]).
    // 4096 floats per tile / 256 threads = 4 float4 loads each.
#pragma unroll
    for (int l = 0; l < 4; ++l) {
      const int idx = tid + l * THREADS;     // 0..1023
      const int r = idx >> 3;                // 0..127
      const int c4 = (idx & 7) << 2;         // 0,4,...,28
      const float4 av = *reinterpret_cast<const float4*>(
          &A[(size_t)(bi + r) * DD + kt + c4]);
      As[c4 + 0][r] = av.x;
      As[c4 + 1][r] = av.y;
      As[c4 + 2][r] = av.z;
      As[c4 + 3][r] = av.w;
      const float4 bv = *reinterpret_cast<const float4*>(
          &B[(size_t)(bj + r) * DD + kt + c4]);
      Bs[c4 + 0][r] = bv.x;
      Bs[c4 + 1][r] = bv.y;
      Bs[c4 + 2][r] = bv.z;
      Bs[c4 + 3][r] = bv.w;
    }
    __syncthreads();

#pragma unroll
    for (int k = 0; k < BK; ++k) {
      const float4 a0 = *reinterpret_cast<const float4*>(&As[k][ty * TM]);
      const float4 a1 = *reinterpret_cast<const float4*>(&As[k][ty * TM + 4]);
      const float4 b0 = *reinterpret_cast<const float4*>(&Bs[k][tx * TN]);
      const float4 b1 = *reinterpret_cast<const float4*>(&Bs[k][tx * TN + 4]);
      const float av[TM] = {a0.x, a0.y, a0.z, a0.w, a1.x, a1.y, a1.z, a1.w};
      const float bv[TN] = {b0.x, b0.y, b0.z, b0.w, b1.x, b1.y, b1.z, b1.w};
#pragma unroll
      for (int i = 0; i < TM; ++i) a2[i] = fmaf(av[i], av[i], a2[i]);
#pragma unroll
      for (int j = 0; j < TN; ++j) b2[j] = fmaf(bv[j], bv[j], b2[j]);
#pragma unroll
      for (int i = 0; i < TM; ++i)
#pragma unroll
        for (int j = 0; j < TN; ++j)
          acc[i][j] = fmaf(av[i], bv[j], acc[i][j]);
    }
    __syncthreads();
  }

  // Epilogue: k = exp((2*dot - |a|^2 - |b|^2) / 16384), accumulate in fp64.
  double local = 0.0;
#pragma unroll
  for (int i = 0; i < TM; ++i) {
#pragma unroll
    for (int j = 0; j < TN; ++j) {
      const float arg = (2.0f * acc[i][j] - a2[i] - b2[j]) * (1.0f / 16384.0f);
      local += (double)expf(arg);
    }
  }

  red[tid] = local;
  __syncthreads();
  for (int s = THREADS / 2; s > 0; s >>= 1) {
    if (tid < s) red[tid] += red[tid + s];
    __syncthreads();
  }
  if (tid == 0) atomicAdd(&sums[mode], red[0]);
}

__global__ void zero_sums(double* __restrict__ s) {
  if (threadIdx.x < 3) s[threadIdx.x] = 0.0;
}

__global__ void finish(const double* __restrict__ s, float* __restrict__ out) {
  const double inv = 1.0 / ((double)NN * (double)NN);
  out[0] = (float)((s[0] + s[1] - 2.0 * s[2]) * inv);
}

extern "C" void kernel_launch(void* const* d_in, const int* in_sizes, int n_in,
                              void* d_out, int out_size, void* d_ws, size_t ws_size,
                              hipStream_t stream) {
  const float* y_inputs = (const float*)d_in[0];  // "inputs"
  const float* x_true   = (const float*)d_in[1];  // "true_samples"
  float* out = (float*)d_out;
  double* sums = (double*)d_ws;                   // 3 doubles of scratch

  zero_sums<<<1, 64, 0, stream>>>(sums);
  dim3 grid(NN / BN, NN / BM, 3);
  mmd_pairsum<<<grid, THREADS, 0, stream>>>(x_true, y_inputs, sums);
  finish<<<1, 1, 0, stream>>>(sums, out);
}

// Round 2
// 369.158 us; speedup vs baseline: 2.1831x; 2.1831x over previous
//
#include <hip/hip_runtime.h>
#include <hip/hip_bf16.h>

// MMD (InfoVAE RBF kernel), N=8192, D=128, fp32 in, scalar fp32 out.
//
// Round 2: split-bf16 MFMA path.
//   x = hi + lo (two RNE bf16 splits); dot(x,y) ~= hi*hi + hi*lo + lo*hi via
//   three chained v_mfma_f32_16x16x32_bf16 into one fp32 accumulator.
//   Dropped lo*lo + residual: per-dot err ~2e-4 -> arg err ~2.6e-8/elem,
//   zero-mean; averages out over 67M elements (<<7.15e-8 threshold).
//   Accumulation of kernel values stays fp64 (cancellation to ~4e-6 rel).
// Symmetry: Kxx/Kyy computed on upper-triangle blocks only, weight 2 off-diag.

#define NN 8192
#define DD 128

typedef __attribute__((ext_vector_type(8))) short bf16x8;
typedef __attribute__((ext_vector_type(4))) float f32x4;

// ---- ws layout ----
// 0            : 3 doubles (sums)
// 256          : normX  (8192 f32, 32 KB)
// 256+32K      : normY  (32 KB)
// 256+64K      : Xhi (2 MB), Xlo, Yhi, Ylo   (8192*128 bf16 each)
constexpr size_t WS_NORMX = 256;
constexpr size_t WS_NORMY = WS_NORMX + NN * sizeof(float);
constexpr size_t WS_XHI   = WS_NORMY + NN * sizeof(float);
constexpr size_t WS_MAT   = (size_t)NN * DD * sizeof(__hip_bfloat16);  // 2 MB

__global__ void zero_sums(double* __restrict__ s) {
  if (threadIdx.x < 3) s[threadIdx.x] = 0.0;
}

// One wave per row: split fp32 row into hi/lo bf16 + fp32 norm.
__global__ __launch_bounds__(256) void prep(
    const float* __restrict__ src, __hip_bfloat16* __restrict__ hi,
    __hip_bfloat16* __restrict__ lo, float* __restrict__ norms) {
  const int row = blockIdx.x * 4 + (threadIdx.x >> 6);
  const int lane = threadIdx.x & 63;
  const float2 v = *reinterpret_cast<const float2*>(src + (size_t)row * DD + 2 * lane);

  float n = v.x * v.x + v.y * v.y;
  __hip_bfloat16 h0 = __float2bfloat16(v.x);
  __hip_bfloat16 h1 = __float2bfloat16(v.y);
  __hip_bfloat16 l0 = __float2bfloat16(v.x - __bfloat162float(h0));
  __hip_bfloat16 l1 = __float2bfloat16(v.y - __bfloat162float(h1));
  *reinterpret_cast<__hip_bfloat162*>(hi + (size_t)row * DD + 2 * lane) =
      __hip_bfloat162{h0, h1};
  *reinterpret_cast<__hip_bfloat162*>(lo + (size_t)row * DD + 2 * lane) =
      __hip_bfloat162{l0, l1};

#pragma unroll
  for (int o = 32; o > 0; o >>= 1) n += __shfl_down(n, o);
  if (lane == 0) norms[row] = n;
}

__global__ __launch_bounds__(256) void mmd_mfma(
    const __hip_bfloat16* __restrict__ Xhi, const __hip_bfloat16* __restrict__ Xlo,
    const __hip_bfloat16* __restrict__ Yhi, const __hip_bfloat16* __restrict__ Ylo,
    const float* __restrict__ normX, const float* __restrict__ normY,
    double* __restrict__ sums) {
  const int mode = blockIdx.z;         // 0: xx, 1: yy, 2: xy
  const int bib = blockIdx.y, bjb = blockIdx.x;
  if (mode < 2 && bjb < bib) return;   // symmetric modes: upper triangle only

  const __hip_bfloat16* __restrict__ Ahi = (mode == 1) ? Yhi : Xhi;
  const __hip_bfloat16* __restrict__ Alo = (mode == 1) ? Ylo : Xlo;
  const __hip_bfloat16* __restrict__ Bhi = (mode == 0) ? Xhi : Yhi;
  const __hip_bfloat16* __restrict__ Blo = (mode == 0) ? Xlo : Ylo;
  const float* __restrict__ nA = (mode == 1) ? normY : normX;
  const float* __restrict__ nB = (mode == 0) ? normX : normY;
  const int bi = bib * 128, bj = bjb * 128;

  __shared__ float rowN[128], colN[128];
  __shared__ double red[4];

  const int tid = threadIdx.x;
  const int lane = tid & 63, wave = tid >> 6;
  const int wr = wave >> 1, wc = wave & 1;     // 2x2 wave grid over 128x128
  const int lr = lane & 15, quad = lane >> 4;  // MFMA lane decomposition

  if (tid < 128) rowN[tid] = nA[bi + tid];
  else           colN[tid - 128] = nB[bj + tid - 128];

  // Per-lane row pointers (A-frag: lane holds A[m=lr][k=quad*8 .. +7]).
  const size_t kq = (size_t)quad * 8;
  const __hip_bfloat16* pAhi[4];
  const __hip_bfloat16* pAlo[4];
  const __hip_bfloat16* pBhi[4];
  const __hip_bfloat16* pBlo[4];
#pragma unroll
  for (int i = 0; i < 4; ++i) {
    const size_t ra = (size_t)(bi + wr * 64 + i * 16 + lr) * DD + kq;
    const size_t rb = (size_t)(bj + wc * 64 + i * 16 + lr) * DD + kq;
    pAhi[i] = Ahi + ra;  pAlo[i] = Alo + ra;
    pBhi[i] = Bhi + rb;  pBlo[i] = Blo + rb;
  }

  f32x4 acc[4][4] = {};
#pragma unroll
  for (int ks = 0; ks < 4; ++ks) {
    const int k0 = ks * 32;
    bf16x8 ah[4], al[4], bh[4], bl[4];
#pragma unroll
    for (int i = 0; i < 4; ++i) {
      ah[i] = *reinterpret_cast<const bf16x8*>(pAhi[i] + k0);
      al[i] = *reinterpret_cast<const bf16x8*>(pAlo[i] + k0);
      bh[i] = *reinterpret_cast<const bf16x8*>(pBhi[i] + k0);
      bl[i] = *reinterpret_cast<const bf16x8*>(pBlo[i] + k0);
    }
#pragma unroll
    for (int i = 0; i < 4; ++i) {
#pragma unroll
      for (int j = 0; j < 4; ++j) {
        acc[i][j] = __builtin_amdgcn_mfma_f32_16x16x32_bf16(ah[i], bh[j], acc[i][j], 0, 0, 0);
        acc[i][j] = __builtin_amdgcn_mfma_f32_16x16x32_bf16(ah[i], bl[j], acc[i][j], 0, 0, 0);
        acc[i][j] = __builtin_amdgcn_mfma_f32_16x16x32_bf16(al[i], bh[j], acc[i][j], 0, 0, 0);
      }
    }
  }

  __syncthreads();  // rowN/colN ready

  // Epilogue: C/D layout col=lane&15, row=quad*4+reg (m89-verified).
  double local = 0.0;
#pragma unroll
  for (int i = 0; i < 4; ++i) {
    float a2r[4];
#pragma unroll
    for (int r = 0; r < 4; ++r) a2r[r] = rowN[wr * 64 + i * 16 + quad * 4 + r];
#pragma unroll
    for (int j = 0; j < 4; ++j) {
      const float b2 = colN[wc * 64 + j * 16 + lr];
#pragma unroll
      for (int r = 0; r < 4; ++r) {
        const float arg = (2.0f * acc[i][j][r] - a2r[r] - b2) * (1.0f / 16384.0f);
        local += (double)expf(arg);
      }
    }
  }
  if (mode < 2 && bib != bjb) local *= 2.0;  // mirrored block

#pragma unroll
  for (int o = 32; o > 0; o >>= 1) local += __shfl_down(local, o);
  if (lane == 0) red[wave] = local;
  __syncthreads();
  if (tid == 0) atomicAdd(&sums[mode], red[0] + red[1] + red[2] + red[3]);
}

__global__ void finish(const double* __restrict__ s, float* __restrict__ out) {
  const double inv = 1.0 / ((double)NN * (double)NN);
  out[0] = (float)((s[0] + s[1] - 2.0 * s[2]) * inv);
}

extern "C" void kernel_launch(void* const* d_in, const int* in_sizes, int n_in,
                              void* d_out, int out_size, void* d_ws, size_t ws_size,
                              hipStream_t stream) {
  const float* y_inputs = (const float*)d_in[0];  // "inputs"
  const float* x_true   = (const float*)d_in[1];  // "true_samples"
  float* out = (float*)d_out;

  char* ws = (char*)d_ws;
  double* sums = (double*)ws;
  float* normX = (float*)(ws + WS_NORMX);
  float* normY = (float*)(ws + WS_NORMY);
  __hip_bfloat16* Xhi = (__hip_bfloat16*)(ws + WS_XHI);
  __hip_bfloat16* Xlo = Xhi + (size_t)NN * DD;
  __hip_bfloat16* Yhi = Xlo + (size_t)NN * DD;
  __hip_bfloat16* Ylo = Yhi + (size_t)NN * DD;

  zero_sums<<<1, 64, 0, stream>>>(sums);
  prep<<<NN / 4, 256, 0, stream>>>(x_true, Xhi, Xlo, normX);
  prep<<<NN / 4, 256, 0, stream>>>(y_inputs, Yhi, Ylo, normY);
  dim3 grid(NN / 128, NN / 128, 3);
  mmd_mfma<<<grid, 256, 0, stream>>>(Xhi, Xlo, Yhi, Ylo, normX, normY, sums);
  finish<<<1, 1, 0, stream>>>(sums, out);
}

// Round 3
// 212.255 us; speedup vs baseline: 3.7969x; 1.7392x over previous
//
#include <hip/hip_runtime.h>
#include <hip/hip_bf16.h>

// MMD (InfoVAE RBF kernel), N=8192, D=128, fp32 in, scalar fp32 out.
//
// Round 3: single-bf16 MFMA (dropped the lo-split).
//   Numerics: per-element arg error std ~2.5e-6, zero-mean (RNE symmetric);
//   mean over 67M pairs shifts MMD by ~2e-9 << 1.19e-8 margin
//   (current absmax 5.96e-8 vs 7.15e-8 threshold is fp32-reference noise).
//   Row norms stay exact fp32; kernel-value accumulation stays fp64
//   (the three ~6.6e7 sums cancel to ~4e-6 relative).
// Symmetry: Kxx/Kyy upper-triangle blocks only, weight 2 off-diagonal.

#define NN 8192
#define DD 128

typedef __attribute__((ext_vector_type(8))) short bf16x8;
typedef __attribute__((ext_vector_type(4))) float f32x4;

// ---- ws layout ----
constexpr size_t WS_NORMX = 256;
constexpr size_t WS_NORMY = WS_NORMX + NN * sizeof(float);
constexpr size_t WS_XHI   = WS_NORMY + NN * sizeof(float);

__global__ void zero_sums(double* __restrict__ s) {
  if (threadIdx.x < 3) s[threadIdx.x] = 0.0;
}

// One wave per row: cast fp32 row to bf16 + fp32 norm. blockIdx.y picks X/Y.
__global__ __launch_bounds__(256) void prep(
    const float* __restrict__ srcX, const float* __restrict__ srcY,
    __hip_bfloat16* __restrict__ hiX, __hip_bfloat16* __restrict__ hiY,
    float* __restrict__ normX, float* __restrict__ normY) {
  const float* __restrict__ src = blockIdx.y ? srcY : srcX;
  __hip_bfloat16* __restrict__ hi = blockIdx.y ? hiY : hiX;
  float* __restrict__ norms = blockIdx.y ? normY : normX;

  const int row = blockIdx.x * 4 + (threadIdx.x >> 6);
  const int lane = threadIdx.x & 63;
  const float2 v = *reinterpret_cast<const float2*>(src + (size_t)row * DD + 2 * lane);

  float n = v.x * v.x + v.y * v.y;
  __hip_bfloat16 h0 = __float2bfloat16(v.x);
  __hip_bfloat16 h1 = __float2bfloat16(v.y);
  *reinterpret_cast<__hip_bfloat162*>(hi + (size_t)row * DD + 2 * lane) =
      __hip_bfloat162{h0, h1};

#pragma unroll
  for (int o = 32; o > 0; o >>= 1) n += __shfl_down(n, o);
  if (lane == 0) norms[row] = n;
}

__global__ __launch_bounds__(256) void mmd_mfma(
    const __hip_bfloat16* __restrict__ Xh, const __hip_bfloat16* __restrict__ Yh,
    const float* __restrict__ normX, const float* __restrict__ normY,
    double* __restrict__ sums) {
  const int mode = blockIdx.z;         // 0: xx, 1: yy, 2: xy
  const int bib = blockIdx.y, bjb = blockIdx.x;
  if (mode < 2 && bjb < bib) return;   // symmetric modes: upper triangle only

  const __hip_bfloat16* __restrict__ A = (mode == 1) ? Yh : Xh;
  const __hip_bfloat16* __restrict__ B = (mode == 0) ? Xh : Yh;
  const float* __restrict__ nA = (mode == 1) ? normY : normX;
  const float* __restrict__ nB = (mode == 0) ? normX : normY;
  const int bi = bib * 128, bj = bjb * 128;

  __shared__ float rowN[128], colN[128];
  __shared__ double red[4];

  const int tid = threadIdx.x;
  const int lane = tid & 63, wave = tid >> 6;
  const int wr = wave >> 1, wc = wave & 1;     // 2x2 wave grid over 128x128
  const int lr = lane & 15, quad = lane >> 4;  // MFMA lane decomposition

  if (tid < 128) rowN[tid] = nA[bi + tid];
  else           colN[tid - 128] = nB[bj + tid - 128];

  // A-frag: lane holds A[m=lr][k=quad*8 .. +7] per 16x16x32 step.
  const size_t kq = (size_t)quad * 8;
  const __hip_bfloat16* pA[4];
  const __hip_bfloat16* pB[4];
#pragma unroll
  for (int i = 0; i < 4; ++i) {
    pA[i] = A + (size_t)(bi + wr * 64 + i * 16 + lr) * DD + kq;
    pB[i] = B + (size_t)(bj + wc * 64 + i * 16 + lr) * DD + kq;
  }

  f32x4 acc[4][4] = {};
#pragma unroll
  for (int ks = 0; ks < 4; ++ks) {
    const int k0 = ks * 32;
    bf16x8 a[4], b[4];
#pragma unroll
    for (int i = 0; i < 4; ++i) {
      a[i] = *reinterpret_cast<const bf16x8*>(pA[i] + k0);
      b[i] = *reinterpret_cast<const bf16x8*>(pB[i] + k0);
    }
#pragma unroll
    for (int i = 0; i < 4; ++i)
#pragma unroll
      for (int j = 0; j < 4; ++j)
        acc[i][j] = __builtin_amdgcn_mfma_f32_16x16x32_bf16(a[i], b[j], acc[i][j], 0, 0, 0);
  }

  __syncthreads();  // rowN/colN ready

  // Epilogue: C/D layout col=lane&15, row=quad*4+reg (m89-verified).
  double local = 0.0;
#pragma unroll
  for (int i = 0; i < 4; ++i) {
    float a2r[4];
#pragma unroll
    for (int r = 0; r < 4; ++r) a2r[r] = rowN[wr * 64 + i * 16 + quad * 4 + r];
#pragma unroll
    for (int j = 0; j < 4; ++j) {
      const float b2 = colN[wc * 64 + j * 16 + lr];
#pragma unroll
      for (int r = 0; r < 4; ++r) {
        const float arg = (2.0f * acc[i][j][r] - a2r[r] - b2) * (1.0f / 16384.0f);
        local += (double)expf(arg);
      }
    }
  }
  if (mode < 2 && bib != bjb) local *= 2.0;  // mirrored block

#pragma unroll
  for (int o = 32; o > 0; o >>= 1) local += __shfl_down(local, o);
  if (lane == 0) red[wave] = local;
  __syncthreads();
  if (tid == 0) atomicAdd(&sums[mode], red[0] + red[1] + red[2] + red[3]);
}

__global__ void finish(const double* __restrict__ s, float* __restrict__ out) {
  const double inv = 1.0 / ((double)NN * (double)NN);
  out[0] = (float)((s[0] + s[1] - 2.0 * s[2]) * inv);
}

extern "C" void kernel_launch(void* const* d_in, const int* in_sizes, int n_in,
                              void* d_out, int out_size, void* d_ws, size_t ws_size,
                              hipStream_t stream) {
  const float* y_inputs = (const float*)d_in[0];  // "inputs"
  const float* x_true   = (const float*)d_in[1];  // "true_samples"
  float* out = (float*)d_out;

  char* ws = (char*)d_ws;
  double* sums = (double*)ws;
  float* normX = (float*)(ws + WS_NORMX);
  float* normY = (float*)(ws + WS_NORMY);
  __hip_bfloat16* Xh = (__hip_bfloat16*)(ws + WS_XHI);
  __hip_bfloat16* Yh = Xh + (size_t)NN * DD;

  zero_sums<<<1, 64, 0, stream>>>(sums);
  dim3 pgrid(NN / 4, 2);
  prep<<<pgrid, 256, 0, stream>>>(x_true, y_inputs, Xh, Yh, normX, normY);
  dim3 grid(NN / 128, NN / 128, 3);
  mmd_mfma<<<grid, 256, 0, stream>>>(Xh, Yh, normX, normY, sums);
  finish<<<1, 1, 0, stream>>>(sums, out);
}

// Round 4
// 207.278 us; speedup vs baseline: 3.8881x; 1.0240x over previous
//
#include <hip/hip_runtime.h>
#include <hip/hip_bf16.h>

// MMD (InfoVAE RBF kernel), N=8192, D=128, fp32 in, scalar fp32 out.
//
// Round 4: epilogue VALU diet.
//   - exp via raw v_exp_f32 (exp2): norms stored pre-scaled by -log2e/16384,
//     so per element: 1 add + 1 fma + 1 exp2 + 1 fp32 accumulate.
//     HW exp2 bias is identical across Kxx/Kyy/Kxy arg distributions ->
//     cancels in +1+1-2; residual noise ~4e-11 in the MMD.
//   - per-thread accumulation fp32 (partials <= 16, rounding -> ~2e-10 MMD),
//     one fp64 convert per thread; cross-wave/block reduction stays fp64.
//   - zero_sums fused into prep (stream-order guarantees visibility).
// bf16 single-split MFMA as round 3 (arg noise zero-mean, ~2e-9 MMD shift).
// Symmetry: Kxx/Kyy upper-triangle blocks only, weight 2 off-diagonal.

#define NN 8192
#define DD 128

typedef __attribute__((ext_vector_type(8))) short bf16x8;
typedef __attribute__((ext_vector_type(4))) float f32x4;

#if __has_builtin(__builtin_amdgcn_exp2f)
#define EXP2F __builtin_amdgcn_exp2f
#else
#define EXP2F exp2f
#endif

constexpr float LOG2E = 0x1.715476p+0f;            // log2(e)
constexpr float S2 = LOG2E / 8192.0f;              // 2*log2e/16384

// ---- ws layout ----
constexpr size_t WS_NORMX = 256;
constexpr size_t WS_NORMY = WS_NORMX + NN * sizeof(float);
constexpr size_t WS_XHI   = WS_NORMY + NN * sizeof(float);

// One wave per row: cast fp32 row to bf16 + pre-scaled fp32 norm.
// Block (0,0) also zeroes the fp64 sums (kernel completes before mmd_mfma).
__global__ __launch_bounds__(256) void prep(
    const float* __restrict__ srcX, const float* __restrict__ srcY,
    __hip_bfloat16* __restrict__ hiX, __hip_bfloat16* __restrict__ hiY,
    float* __restrict__ normX, float* __restrict__ normY,
    double* __restrict__ sums) {
  if (blockIdx.x == 0 && blockIdx.y == 0 && threadIdx.x < 3)
    sums[threadIdx.x] = 0.0;

  const float* __restrict__ src = blockIdx.y ? srcY : srcX;
  __hip_bfloat16* __restrict__ hi = blockIdx.y ? hiY : hiX;
  float* __restrict__ norms = blockIdx.y ? normY : normX;

  const int row = blockIdx.x * 4 + (threadIdx.x >> 6);
  const int lane = threadIdx.x & 63;
  const float2 v = *reinterpret_cast<const float2*>(src + (size_t)row * DD + 2 * lane);

  float n = v.x * v.x + v.y * v.y;
  __hip_bfloat16 h0 = __float2bfloat16(v.x);
  __hip_bfloat16 h1 = __float2bfloat16(v.y);
  *reinterpret_cast<__hip_bfloat162*>(hi + (size_t)row * DD + 2 * lane) =
      __hip_bfloat162{h0, h1};

#pragma unroll
  for (int o = 32; o > 0; o >>= 1) n += __shfl_down(n, o);
  if (lane == 0) norms[row] = n * (-LOG2E / 16384.0f);  // pre-scaled
}

__global__ __launch_bounds__(256) void mmd_mfma(
    const __hip_bfloat16* __restrict__ Xh, const __hip_bfloat16* __restrict__ Yh,
    const float* __restrict__ normX, const float* __restrict__ normY,
    double* __restrict__ sums) {
  const int mode = blockIdx.z;         // 0: xx, 1: yy, 2: xy
  const int bib = blockIdx.y, bjb = blockIdx.x;
  if (mode < 2 && bjb < bib) return;   // symmetric modes: upper triangle only

  const __hip_bfloat16* __restrict__ A = (mode == 1) ? Yh : Xh;
  const __hip_bfloat16* __restrict__ B = (mode == 0) ? Xh : Yh;
  const float* __restrict__ nA = (mode == 1) ? normY : normX;
  const float* __restrict__ nB = (mode == 0) ? normX : normY;
  const int bi = bib * 128, bj = bjb * 128;

  __shared__ float rowN[128], colN[128];
  __shared__ double red[4];

  const int tid = threadIdx.x;
  const int lane = tid & 63, wave = tid >> 6;
  const int wr = wave >> 1, wc = wave & 1;     // 2x2 wave grid over 128x128
  const int lr = lane & 15, quad = lane >> 4;  // MFMA lane decomposition

  if (tid < 128) rowN[tid] = nA[bi + tid];
  else           colN[tid - 128] = nB[bj + tid - 128];

  // A-frag: lane holds A[m=lr][k=quad*8 .. +7] per 16x16x32 step.
  const size_t kq = (size_t)quad * 8;
  const __hip_bfloat16* pA[4];
  const __hip_bfloat16* pB[4];
#pragma unroll
  for (int i = 0; i < 4; ++i) {
    pA[i] = A + (size_t)(bi + wr * 64 + i * 16 + lr) * DD + kq;
    pB[i] = B + (size_t)(bj + wc * 64 + i * 16 + lr) * DD + kq;
  }

  f32x4 acc[4][4] = {};
#pragma unroll
  for (int ks = 0; ks < 4; ++ks) {
    const int k0 = ks * 32;
    bf16x8 a[4], b[4];
#pragma unroll
    for (int i = 0; i < 4; ++i) {
      a[i] = *reinterpret_cast<const bf16x8*>(pA[i] + k0);
      b[i] = *reinterpret_cast<const bf16x8*>(pB[i] + k0);
    }
#pragma unroll
    for (int i = 0; i < 4; ++i)
#pragma unroll
      for (int j = 0; j < 4; ++j)
        acc[i][j] = __builtin_amdgcn_mfma_f32_16x16x32_bf16(a[i], b[j], acc[i][j], 0, 0, 0);
  }

  __syncthreads();  // rowN/colN ready

  // Epilogue: C/D layout col=lane&15, row=quad*4+reg (m89-verified).
  // k(arg) = exp2(acc*S2 + ra + rb) with ra,rb pre-scaled -norm*log2e/16384.
  float part[4] = {0.f, 0.f, 0.f, 0.f};
#pragma unroll
  for (int i = 0; i < 4; ++i) {
    float ar[4];
#pragma unroll
    for (int r = 0; r < 4; ++r) ar[r] = rowN[wr * 64 + i * 16 + quad * 4 + r];
#pragma unroll
    for (int j = 0; j < 4; ++j) {
      const float rb = colN[wc * 64 + j * 16 + lr];
#pragma unroll
      for (int r = 0; r < 4; ++r)
        part[r] += EXP2F(fmaf(acc[i][j][r], S2, ar[r] + rb));
    }
  }
  double local = (double)((part[0] + part[1]) + (part[2] + part[3]));
  if (mode < 2 && bib != bjb) local *= 2.0;  // mirrored block

#pragma unroll
  for (int o = 32; o > 0; o >>= 1) local += __shfl_down(local, o);
  if (lane == 0) red[wave] = local;
  __syncthreads();
  if (tid == 0) atomicAdd(&sums[mode], red[0] + red[1] + red[2] + red[3]);
}

__global__ void finish(const double* __restrict__ s, float* __restrict__ out) {
  const double inv = 1.0 / ((double)NN * (double)NN);
  out[0] = (float)((s[0] + s[1] - 2.0 * s[2]) * inv);
}

extern "C" void kernel_launch(void* const* d_in, const int* in_sizes, int n_in,
                              void* d_out, int out_size, void* d_ws, size_t ws_size,
                              hipStream_t stream) {
  const float* y_inputs = (const float*)d_in[0];  // "inputs"
  const float* x_true   = (const float*)d_in[1];  // "true_samples"
  float* out = (float*)d_out;

  char* ws = (char*)d_ws;
  double* sums = (double*)ws;
  float* normX = (float*)(ws + WS_NORMX);
  float* normY = (float*)(ws + WS_NORMY);
  __hip_bfloat16* Xh = (__hip_bfloat16*)(ws + WS_XHI);
  __hip_bfloat16* Yh = Xh + (size_t)NN * DD;

  dim3 pgrid(NN / 4, 2);
  prep<<<pgrid, 256, 0, stream>>>(x_true, y_inputs, Xh, Yh, normX, normY, sums);
  dim3 grid(NN / 128, NN / 128, 3);
  mmd_mfma<<<grid, 256, 0, stream>>>(Xh, Yh, normX, normY, sums);
  finish<<<1, 1, 0, stream>>>(sums, out);
}

// Round 5
// 133.824 us; speedup vs baseline: 6.0222x; 1.5489x over previous
//
#include <hip/hip_runtime.h>
#include <hip/hip_bf16.h>
#include <math.h>

// MMD (InfoVAE RBF kernel), N=8192, D=128, fp32 in, scalar fp32 out.
//
// Round 5: latency restructure.
//   Unified Z = [X;Y] (16384 x 128): MMD*N^2 = sum_{i,j} s_i s_j k(z_i,z_j),
//   s=+1 (X rows), -1 (Y rows). Symmetric -> upper-triangle 128x128 blocks
//   (8256 total, 1D grid, no early-exits). 128 | 8192 so each block's sign
//   is a uniform scalar weight (+-1, x2 off-diagonal).
//   Panels staged cooperatively into LDS (two K=64 phases, padded stride
//   144 B -> conflict-spread ds_read_b128), replacing per-wave direct-L2
//   fragment loads (the round-4 latency bottleneck: MfmaUtil 8.7 / VALU 18.5
//   / both idle). Halves L2 traffic, amortizes latency over one bulk stage.
//   Numerics: bf16 single-split MFMA (zero-mean arg noise ~2.5e-6/elem ->
//   ~2e-9 MMD shift); exp2 via v_exp_f32 with pre-scaled norms; per-thread
//   fp32 partials (<=16); fp64 block/global accumulation (64-slot spread).

#define NN 8192
#define DD 128
#define TZ 16384
#define TILES 128

typedef __attribute__((ext_vector_type(8))) short bf16x8;
typedef __attribute__((ext_vector_type(4))) float f32x4;

#if __has_builtin(__builtin_amdgcn_exp2f)
#define EXP2F __builtin_amdgcn_exp2f
#else
#define EXP2F exp2f
#endif

constexpr float LOG2E = 0x1.715476p+0f;
constexpr float S2 = LOG2E / 8192.0f;              // 2*log2e/16384

constexpr int ROWB = 144;                          // LDS row stride (128B data + 16B pad)
constexpr int PANEL = 128 * ROWB;                  // 18432 B per panel

// ---- ws layout ----
constexpr size_t WS_NORM = 512;                                  // 64 doubles first
constexpr size_t WS_Z    = WS_NORM + (size_t)TZ * sizeof(float);

// One wave per row of Z: cast to bf16 + pre-scaled fp32 norm. Block 0 zeroes
// the 64 partial-sum slots (prep completes before mmd_mfma in stream order).
__global__ __launch_bounds__(256) void prep(
    const float* __restrict__ X, const float* __restrict__ Y,
    __hip_bfloat16* __restrict__ Z, float* __restrict__ normZ,
    double* __restrict__ sums) {
  if (blockIdx.x == 0 && threadIdx.x < 64) sums[threadIdx.x] = 0.0;

  const int row = blockIdx.x * 4 + (threadIdx.x >> 6);
  const int lane = threadIdx.x & 63;
  const float* __restrict__ src =
      (row < NN) ? (X + (size_t)row * DD) : (Y + (size_t)(row - NN) * DD);
  const float2 v = *reinterpret_cast<const float2*>(src + 2 * lane);

  float n = v.x * v.x + v.y * v.y;
  *reinterpret_cast<__hip_bfloat162*>(Z + (size_t)row * DD + 2 * lane) =
      __hip_bfloat162{__float2bfloat16(v.x), __float2bfloat16(v.y)};

#pragma unroll
  for (int o = 32; o > 0; o >>= 1) n += __shfl_down(n, o);
  if (lane == 0) normZ[row] = n * (-LOG2E / 16384.0f);  // pre-scaled
}

__device__ __forceinline__ int tri_start(int i) {    // row-major upper-tri row start
  return i * TILES - (i * (i - 1)) / 2;
}

__global__ __launch_bounds__(256) void mmd_mfma(
    const __hip_bfloat16* __restrict__ Z, const float* __restrict__ normZ,
    double* __restrict__ sums) {
  __shared__ alignas(16) char lds[2 * PANEL];
  __shared__ float rowN[128], colN[128];
  __shared__ double red[4];

  const int t = blockIdx.x;
  // Unrank t -> (I,J), I<=J<128: I from quadratic, exact fixup.
  int I = (int)((257.0 - sqrt(257.0 * 257.0 - 8.0 * (double)t)) * 0.5);
  if (I > 127) I = 127;
  if (I < 0) I = 0;
  while (I < 127 && tri_start(I + 1) <= t) ++I;
  while (I > 0 && tri_start(I) > t) --I;
  const int J = I + (t - tri_start(I));

  const int tid = threadIdx.x;
  const int lane = tid & 63, wave = tid >> 6;
  const int wr = wave >> 1, wc = wave & 1;       // 2x2 wave grid over 128x128
  const int lr = lane & 15, quad = lane >> 4;    // MFMA lane decomposition

  if (tid < 128) rowN[tid] = normZ[I * 128 + tid];
  else           colN[tid - 128] = normZ[J * 128 + tid - 128];

  const uint4* __restrict__ zu = reinterpret_cast<const uint4*>(Z);

  f32x4 acc[4][4] = {};
#pragma unroll
  for (int p = 0; p < 2; ++p) {
    __syncthreads();  // LDS reusable (also publishes rowN/colN on p==0)
    // Stage 2 panels x 128 rows x 64 K-elems (128 B) = 32 KB, coalesced.
#pragma unroll
    for (int l = 0; l < 8; ++l) {
      const int idx = tid + l * 256;             // 0..2047 chunks of 16 B
      const int panel = idx >> 10;
      const int row = (idx >> 3) & 127;
      const int c = idx & 7;
      const int grow = (panel ? J : I) * 128 + row;
      const uint4 v = zu[(size_t)grow * 16 + p * 8 + c];
      *reinterpret_cast<uint4*>(&lds[panel * PANEL + row * ROWB + c * 16]) = v;
    }
    __syncthreads();

#pragma unroll
    for (int ks = 0; ks < 2; ++ks) {
      bf16x8 a[4], b[4];
#pragma unroll
      for (int i = 0; i < 4; ++i) {
        a[i] = *reinterpret_cast<const bf16x8*>(
            &lds[(wr * 64 + i * 16 + lr) * ROWB + ks * 64 + quad * 16]);
        b[i] = *reinterpret_cast<const bf16x8*>(
            &lds[PANEL + (wc * 64 + i * 16 + lr) * ROWB + ks * 64 + quad * 16]);
      }
#pragma unroll
      for (int i = 0; i < 4; ++i)
#pragma unroll
        for (int j = 0; j < 4; ++j)
          acc[i][j] = __builtin_amdgcn_mfma_f32_16x16x32_bf16(a[i], b[j], acc[i][j], 0, 0, 0);
    }
  }

  // Epilogue: C/D layout col=lane&15, row=quad*4+reg (m89-verified).
  // k = exp2(acc*S2 + ra + rb), ra/rb pre-scaled -norm*log2e/16384.
  float part[4] = {0.f, 0.f, 0.f, 0.f};
#pragma unroll
  for (int i = 0; i < 4; ++i) {
    float ar[4];
#pragma unroll
    for (int r = 0; r < 4; ++r) ar[r] = rowN[wr * 64 + i * 16 + quad * 4 + r];
#pragma unroll
    for (int j = 0; j < 4; ++j) {
      const float rb = colN[wc * 64 + j * 16 + lr];
#pragma unroll
      for (int r = 0; r < 4; ++r)
        part[r] += EXP2F(fmaf(acc[i][j][r], S2, ar[r] + rb));
    }
  }
  double local = (double)((part[0] + part[1]) + (part[2] + part[3]));
  // Uniform block weight: sign(I)*sign(J), x2 for mirrored off-diag blocks.
  double w = ((I < 64) == (J < 64)) ? 1.0 : -1.0;
  if (I != J) w += w;
  local *= w;

#pragma unroll
  for (int o = 32; o > 0; o >>= 1) local += __shfl_down(local, o);
  if (lane == 0) red[wave] = local;
  __syncthreads();
  if (tid == 0) atomicAdd(&sums[t & 63], red[0] + red[1] + red[2] + red[3]);
}

__global__ void finish(const double* __restrict__ s, float* __restrict__ out) {
  double v = s[threadIdx.x];
#pragma unroll
  for (int o = 32; o > 0; o >>= 1) v += __shfl_down(v, o);
  if (threadIdx.x == 0)
    out[0] = (float)(v * (1.0 / ((double)NN * (double)NN)));
}

extern "C" void kernel_launch(void* const* d_in, const int* in_sizes, int n_in,
                              void* d_out, int out_size, void* d_ws, size_t ws_size,
                              hipStream_t stream) {
  const float* y_inputs = (const float*)d_in[0];  // "inputs"
  const float* x_true   = (const float*)d_in[1];  // "true_samples"
  float* out = (float*)d_out;

  char* ws = (char*)d_ws;
  double* sums = (double*)ws;                     // 64 fp64 partial slots
  float* normZ = (float*)(ws + WS_NORM);
  __hip_bfloat16* Z = (__hip_bfloat16*)(ws + WS_Z);

  prep<<<TZ / 4, 256, 0, stream>>>(x_true, y_inputs, Z, normZ, sums);
  const int nblocks = TILES * (TILES + 1) / 2;    // 8256
  mmd_mfma<<<nblocks, 256, 0, stream>>>(Z, normZ, sums);
  finish<<<1, 64, 0, stream>>>(sums, out);
}

// Round 6
// 117.800 us; speedup vs baseline: 6.8413x; 1.1360x over previous
//
#include <hip/hip_runtime.h>
#include <hip/hip_bf16.h>
#include <math.h>

// MMD (InfoVAE RBF kernel), N=8192, D=128, fp32 in, scalar fp32 out.
//
// Round 6: epilogue packed-fp32 + occupancy push.
//   - Unified Z = [X;Y]: MMD*N^2 = sum s_i s_j k(z_i,z_j); upper-triangle
//     128x128 blocks (8256), uniform +-1/+-2 block weights.
//   - Epilogue on f32x2 (v_pk_add_f32 / v_pk_fma_f32, 2x fp32 rate):
//     per 4 elems: 2 pk_add(base) + 2 pk_fma + 2 pk_add(accum) + 4 exp2,
//     halving the round-5 epilogue VALU issue (~21 -> ~10 us/CU-floor).
//   - __launch_bounds__(256,4): arch VGPR <= 64 (+64 AGPR acc) -> 4 waves/EU;
//     LDS 38.4 KB x 4 = 153.6 KB fits -> 4 blocks/CU (was ~1.5-3 effective).
//   - Staging with per-thread constant (c, r0) and immediate-offset unroll.
//   Numerics unchanged (round-3/4 analysis): bf16 MFMA arg noise zero-mean
//   ~2.5e-6/elem -> ~2e-9 MMD shift; exp2 HW bias cancels in +1+1-2; fp32
//   per-thread partials (<=16) -> ~2e-10; fp64 block/global accumulation.

#define NN 8192
#define DD 128
#define TZ 16384
#define TILES 128

typedef __attribute__((ext_vector_type(8))) short bf16x8;
typedef __attribute__((ext_vector_type(4))) float f32x4;
typedef __attribute__((ext_vector_type(2))) float f32x2;

#if __has_builtin(__builtin_amdgcn_exp2f)
#define EXP2F __builtin_amdgcn_exp2f
#else
#define EXP2F exp2f
#endif

constexpr float LOG2E = 0x1.715476p+0f;
constexpr float S2 = LOG2E / 8192.0f;              // 2*log2e/16384

constexpr int ROWB = 144;                          // LDS row stride per 64-K phase
constexpr int PANEL = 128 * ROWB;                  // 18432 B

// ---- ws layout ----
constexpr size_t WS_NORM = 512;                                  // 64 doubles first
constexpr size_t WS_Z    = WS_NORM + (size_t)TZ * sizeof(float);

__global__ __launch_bounds__(256) void prep(
    const float* __restrict__ X, const float* __restrict__ Y,
    __hip_bfloat16* __restrict__ Z, float* __restrict__ normZ,
    double* __restrict__ sums) {
  if (blockIdx.x == 0 && threadIdx.x < 64) sums[threadIdx.x] = 0.0;

  const int row = blockIdx.x * 4 + (threadIdx.x >> 6);
  const int lane = threadIdx.x & 63;
  const float* __restrict__ src =
      (row < NN) ? (X + (size_t)row * DD) : (Y + (size_t)(row - NN) * DD);
  const float2 v = *reinterpret_cast<const float2*>(src + 2 * lane);

  float n = v.x * v.x + v.y * v.y;
  *reinterpret_cast<__hip_bfloat162*>(Z + (size_t)row * DD + 2 * lane) =
      __hip_bfloat162{__float2bfloat16(v.x), __float2bfloat16(v.y)};

#pragma unroll
  for (int o = 32; o > 0; o >>= 1) n += __shfl_down(n, o);
  if (lane == 0) normZ[row] = n * (-LOG2E / 16384.0f);  // pre-scaled
}

__device__ __forceinline__ int tri_start(int i) {
  return i * TILES - (i * (i - 1)) / 2;
}

__global__ __launch_bounds__(256, 4) void mmd_mfma(
    const __hip_bfloat16* __restrict__ Z, const float* __restrict__ normZ,
    double* __restrict__ sums) {
  __shared__ alignas(16) char lds[2 * PANEL];
  __shared__ float rowN[128], colN[128];
  __shared__ double red[4];

  const int t = blockIdx.x;
  int I = (int)((257.0 - sqrt(257.0 * 257.0 - 8.0 * (double)t)) * 0.5);
  if (I > 127) I = 127;
  if (I < 0) I = 0;
  while (I < 127 && tri_start(I + 1) <= t) ++I;
  while (I > 0 && tri_start(I) > t) --I;
  const int J = I + (t - tri_start(I));

  const int tid = threadIdx.x;
  const int lane = tid & 63, wave = tid >> 6;
  const int wr = wave >> 1, wc = wave & 1;       // 2x2 wave grid over 128x128
  const int lr = lane & 15, quad = lane >> 4;    // MFMA lane decomposition

  if (tid < 128) rowN[tid] = normZ[I * 128 + tid];
  else           colN[tid - 128] = normZ[J * 128 + tid - 128];

  const uint4* __restrict__ zu = reinterpret_cast<const uint4*>(Z);
  // Per-thread staging coords, constant across phases/unroll.
  const int c = tid & 7;                          // 16B chunk in row (0..7)
  const int r0 = tid >> 3;                        // base row (0..31), step 32
  const uint4* gA = zu + (size_t)(I * 128 + r0) * 16 + c;
  const uint4* gB = zu + (size_t)(J * 128 + r0) * 16 + c;
  char* ldsA = lds + r0 * ROWB + c * 16;
  char* ldsB = ldsA + PANEL;

  f32x4 acc[4][4] = {};
#pragma unroll
  for (int p = 0; p < 2; ++p) {
    __syncthreads();  // LDS reusable (also publishes rowN/colN on p==0)
#pragma unroll
    for (int l = 0; l < 4; ++l) {
      const uint4 va = gA[p * 8 + l * 32 * 16];
      const uint4 vb = gB[p * 8 + l * 32 * 16];
      *reinterpret_cast<uint4*>(ldsA + l * 32 * ROWB) = va;
      *reinterpret_cast<uint4*>(ldsB + l * 32 * ROWB) = vb;
    }
    __syncthreads();

#pragma unroll
    for (int ks = 0; ks < 2; ++ks) {
      bf16x8 a[4], b[4];
#pragma unroll
      for (int i = 0; i < 4; ++i) {
        a[i] = *reinterpret_cast<const bf16x8*>(
            &lds[(wr * 64 + i * 16 + lr) * ROWB + ks * 64 + quad * 16]);
        b[i] = *reinterpret_cast<const bf16x8*>(
            &lds[PANEL + (wc * 64 + i * 16 + lr) * ROWB + ks * 64 + quad * 16]);
      }
#pragma unroll
      for (int i = 0; i < 4; ++i)
#pragma unroll
        for (int j = 0; j < 4; ++j)
          acc[i][j] = __builtin_amdgcn_mfma_f32_16x16x32_bf16(a[i], b[j], acc[i][j], 0, 0, 0);
    }
  }

  // Epilogue (C/D layout col=lane&15, row=quad*4+reg), packed fp32 pairs:
  // k = exp2(acc*S2 + ra + rb), ra/rb pre-scaled by -log2e/16384.
  const f32x2 s2v = {S2, S2};
  f32x2 part01 = {0.f, 0.f}, part23 = {0.f, 0.f};
#pragma unroll
  for (int i = 0; i < 4; ++i) {
    const int rbase = wr * 64 + i * 16 + quad * 4;
    const f32x2 ar01 = {rowN[rbase + 0], rowN[rbase + 1]};
    const f32x2 ar23 = {rowN[rbase + 2], rowN[rbase + 3]};
#pragma unroll
    for (int j = 0; j < 4; ++j) {
      const float rb = colN[wc * 64 + j * 16 + lr];
      const f32x2 rb2 = {rb, rb};
      const f32x2 base01 = ar01 + rb2;                       // v_pk_add_f32
      const f32x2 base23 = ar23 + rb2;
      const f32x2 acc01 = {acc[i][j][0], acc[i][j][1]};
      const f32x2 acc23 = {acc[i][j][2], acc[i][j][3]};
      const f32x2 arg01 = __builtin_elementwise_fma(acc01, s2v, base01);  // v_pk_fma_f32
      const f32x2 arg23 = __builtin_elementwise_fma(acc23, s2v, base23);
      const f32x2 e01 = {EXP2F(arg01.x), EXP2F(arg01.y)};
      const f32x2 e23 = {EXP2F(arg23.x), EXP2F(arg23.y)};
      part01 += e01;                                         // v_pk_add_f32
      part23 += e23;
    }
  }
  const f32x2 ps = part01 + part23;
  double local = (double)(ps.x + ps.y);
  double w = ((I < 64) == (J < 64)) ? 1.0 : -1.0;
  if (I != J) w += w;
  local *= w;

#pragma unroll
  for (int o = 32; o > 0; o >>= 1) local += __shfl_down(local, o);
  if (lane == 0) red[wave] = local;
  __syncthreads();
  if (tid == 0) atomicAdd(&sums[t & 63], red[0] + red[1] + red[2] + red[3]);
}

__global__ void finish(const double* __restrict__ s, float* __restrict__ out) {
  double v = s[threadIdx.x];
#pragma unroll
  for (int o = 32; o > 0; o >>= 1) v += __shfl_down(v, o);
  if (threadIdx.x == 0)
    out[0] = (float)(v * (1.0 / ((double)NN * (double)NN)));
}

extern "C" void kernel_launch(void* const* d_in, const int* in_sizes, int n_in,
                              void* d_out, int out_size, void* d_ws, size_t ws_size,
                              hipStream_t stream) {
  const float* y_inputs = (const float*)d_in[0];  // "inputs"
  const float* x_true   = (const float*)d_in[1];  // "true_samples"
  float* out = (float*)d_out;

  char* ws = (char*)d_ws;
  double* sums = (double*)ws;                     // 64 fp64 partial slots
  float* normZ = (float*)(ws + WS_NORM);
  __hip_bfloat16* Z = (__hip_bfloat16*)(ws + WS_Z);

  prep<<<TZ / 4, 256, 0, stream>>>(x_true, y_inputs, Z, normZ, sums);
  const int nblocks = TILES * (TILES + 1) / 2;    // 8256
  mmd_mfma<<<nblocks, 256, 0, stream>>>(Z, normZ, sums);
  finish<<<1, 64, 0, stream>>>(sums, out);
}

// Round 10
// 110.327 us; speedup vs baseline: 7.3047x; 1.0677x over previous
//
#include <hip/hip_runtime.h>
#include <hip/hip_bf16.h>
#include <math.h>

// MMD (InfoVAE RBF kernel), N=8192, D=128, fp32 in, scalar fp32 out.
//
// Round 10: global_load_lds staging WITHOUT the imm-offset argument.
//   r8 and r9 failed with bit-identical absmax 1.49e-3 (r9 had the fused
//   finish reverted) -> deterministic staging bug. Swizzle algebra is
//   verified against r2-r6-passing fragment layouts; the only element never
//   exercised by passing code is the builtin's `offset` arg (introduced in
//   r8 as OFF=128 for phase 1). If that offset applies to the LDS side
//   (not global), phase-1 stripes shift +128 B and the last stripe
//   overflows lds[] into rowN -> garbage norms -> the observed ~1e-3
//   residual (signed +1+1-2 structure cancels pure data garbles to ~1e-6;
//   only norm/weight corruption reaches 1e-3).
//   Fix: OFF=0 always; phase offset folded into the global pointer
//   (identical semantics if offset was global-side; removes the bug if
//   LDS-side). Plus 1 KB sacrificial LDS tail pad.
//   - Unified Z = [X;Y]: MMD*N^2 = sum s_i s_j k(z_i,z_j); upper-triangle
//     128x128 blocks (8256), uniform +-1/+-2 block weights.
//   - Staging via __builtin_amdgcn_global_load_lds(16B): DMA lane-mapping
//     base+lane*16 (m97/m104-verified). XOR swizzle (LDS chunk c of row r
//     holds global chunk c^(r&7)) -> ds_read_b128 spreads 8 lanes per 16B
//     bank-group. LDS ~35 KB -> 4 blocks/CU at launch_bounds(256,4).
//   Numerics (r3-r6): bf16 MFMA arg noise zero-mean -> ~2e-9 MMD shift;
//   exp2 HW bias cancels in +1+1-2; fp32 partials (<=16); fp64 block/
//   global accumulation. absmax held at 5.96e-8 in r1-r6 (threshold 7.15e-8).

#define NN 8192
#define DD 128
#define TZ 16384
#define TILES 128
#define NBLOCKS (TILES * (TILES + 1) / 2)   // 8256

typedef __attribute__((ext_vector_type(8))) short bf16x8;
typedef __attribute__((ext_vector_type(4))) float f32x4;
typedef __attribute__((ext_vector_type(2))) float f32x2;

#if __has_builtin(__builtin_amdgcn_exp2f)
#define EXP2F __builtin_amdgcn_exp2f
#else
#define EXP2F exp2f
#endif

constexpr float LOG2E = 0x1.715476p+0f;
constexpr float S2 = LOG2E / 8192.0f;              // 2*log2e/16384

constexpr int PANEL = 16384;                       // 128 rows x 128 B (one K=64 phase)

// ---- ws layout ----
constexpr size_t WS_NORM = 768;
constexpr size_t WS_Z    = WS_NORM + (size_t)TZ * sizeof(float);

__device__ __forceinline__ void gload_lds16(const void* g, void* l) {
  __builtin_amdgcn_global_load_lds(
      (const __attribute__((address_space(1))) void*)g,
      (__attribute__((address_space(3))) void*)l, 16, 0, 0);
}

__global__ __launch_bounds__(256) void prep(
    const float* __restrict__ X, const float* __restrict__ Y,
    __hip_bfloat16* __restrict__ Z, float* __restrict__ normZ,
    double* __restrict__ sums) {
  if (blockIdx.x == 0 && threadIdx.x < 64) sums[threadIdx.x] = 0.0;

  const int row = blockIdx.x * 4 + (threadIdx.x >> 6);
  const int lane = threadIdx.x & 63;
  const float* __restrict__ src =
      (row < NN) ? (X + (size_t)row * DD) : (Y + (size_t)(row - NN) * DD);
  const float2 v = *reinterpret_cast<const float2*>(src + 2 * lane);

  float n = v.x * v.x + v.y * v.y;
  *reinterpret_cast<__hip_bfloat162*>(Z + (size_t)row * DD + 2 * lane) =
      __hip_bfloat162{__float2bfloat16(v.x), __float2bfloat16(v.y)};

#pragma unroll
  for (int o = 32; o > 0; o >>= 1) n += __shfl_down(n, o);
  if (lane == 0) normZ[row] = n * (-LOG2E / 16384.0f);  // pre-scaled
}

__device__ __forceinline__ int tri_start(int i) {
  return i * TILES - (i * (i - 1)) / 2;
}

__global__ __launch_bounds__(256, 4) void mmd_mfma(
    const __hip_bfloat16* __restrict__ Z, const float* __restrict__ normZ,
    double* __restrict__ sums) {
  __shared__ alignas(16) char lds[2 * PANEL + 1024];  // +1 KB sacrificial pad
  __shared__ float rowN[128], colN[128];
  __shared__ double red[4];

  const int t = blockIdx.x;
  int I = (int)((257.0 - sqrt(257.0 * 257.0 - 8.0 * (double)t)) * 0.5);
  if (I > 127) I = 127;
  if (I < 0) I = 0;
  while (I < 127 && tri_start(I + 1) <= t) ++I;
  while (I > 0 && tri_start(I) > t) --I;
  const int J = I + (t - tri_start(I));

  const int tid = threadIdx.x;
  const int lane = tid & 63, wave = tid >> 6;
  const int wr = wave >> 1, wc = wave & 1;       // 2x2 wave grid over 128x128
  const int lr = lane & 15, quad = lane >> 4;    // MFMA lane decomposition

  if (tid < 128) rowN[tid] = normZ[I * 128 + tid];
  else           colN[tid - 128] = normZ[J * 128 + tid - 128];

  // Staging: lane of wave w, issue l covers row = 8w + (lane>>3) + 32l,
  // LDS chunk c = lane&7 holds global chunk g = c ^ (row&7) (l-invariant).
  // Each global row is 256 B; phase p selects the 128-B half via +p*128
  // folded into the global pointer (NO builtin offset arg).
  const char* Zb = (const char*)Z;
  const int r5 = tid >> 3;                       // 0..31
  const int g = (tid & 7) ^ (r5 & 7);
  const char* gA = Zb + (size_t)I * 32768 + r5 * 256 + g * 16;
  const char* gB = Zb + (size_t)J * 32768 + r5 * 256 + g * 16;
  char* lw = lds + wave * 1024;                  // wave-uniform LDS base

  // MFMA LDS read bases (swizzled chunk: (ks*4+quad) ^ (lr&7), bits disjoint).
  const int aBase = (wr * 64 + lr) * 128;
  const int bBase = PANEL + (wc * 64 + lr) * 128;
  const int sa = lr & 7;

  f32x4 acc[4][4] = {};
#pragma unroll
  for (int p = 0; p < 2; ++p) {
    __syncthreads();  // LDS reuse guard (p0: also publishes rowN/colN)
#pragma unroll
    for (int l = 0; l < 4; ++l) {
      gload_lds16(gA + p * 128 + l * 8192, lw + l * 4096);
      gload_lds16(gB + p * 128 + l * 8192, lw + PANEL + l * 4096);
    }
    __syncthreads();  // drains vmcnt (global_load_lds completion)

#pragma unroll
    for (int ks = 0; ks < 2; ++ks) {
      const int csw = (((ks * 4) + quad) ^ sa) * 16;
      bf16x8 a[4], b[4];
#pragma unroll
      for (int i = 0; i < 4; ++i) {
        a[i] = *reinterpret_cast<const bf16x8*>(&lds[aBase + i * 2048 + csw]);
        b[i] = *reinterpret_cast<const bf16x8*>(&lds[bBase + i * 2048 + csw]);
      }
#pragma unroll
      for (int i = 0; i < 4; ++i)
#pragma unroll
        for (int j = 0; j < 4; ++j)
          acc[i][j] = __builtin_amdgcn_mfma_f32_16x16x32_bf16(a[i], b[j], acc[i][j], 0, 0, 0);
    }
  }

  // Epilogue (C/D: col=lane&15, row=quad*4+reg), packed fp32 pairs:
  // k = exp2(acc*S2 + ra + rb), ra/rb pre-scaled by -log2e/16384.
  const f32x2 s2v = {S2, S2};
  f32x2 part01 = {0.f, 0.f}, part23 = {0.f, 0.f};
#pragma unroll
  for (int i = 0; i < 4; ++i) {
    const int rbase = wr * 64 + i * 16 + quad * 4;
    const f32x2 ar01 = {rowN[rbase + 0], rowN[rbase + 1]};
    const f32x2 ar23 = {rowN[rbase + 2], rowN[rbase + 3]};
#pragma unroll
    for (int j = 0; j < 4; ++j) {
      const float rb = colN[wc * 64 + j * 16 + lr];
      const f32x2 rb2 = {rb, rb};
      const f32x2 base01 = ar01 + rb2;
      const f32x2 base23 = ar23 + rb2;
      const f32x2 acc01 = {acc[i][j][0], acc[i][j][1]};
      const f32x2 acc23 = {acc[i][j][2], acc[i][j][3]};
      const f32x2 arg01 = __builtin_elementwise_fma(acc01, s2v, base01);
      const f32x2 arg23 = __builtin_elementwise_fma(acc23, s2v, base23);
      part01 += (f32x2){EXP2F(arg01.x), EXP2F(arg01.y)};
      part23 += (f32x2){EXP2F(arg23.x), EXP2F(arg23.y)};
    }
  }
  const f32x2 ps = part01 + part23;
  double local = (double)(ps.x + ps.y);
  double w = ((I < 64) == (J < 64)) ? 1.0 : -1.0;
  if (I != J) w += w;
  local *= w;

#pragma unroll
  for (int o = 32; o > 0; o >>= 1) local += __shfl_down(local, o);
  if (lane == 0) red[wave] = local;
  __syncthreads();
  if (tid == 0) atomicAdd(&sums[t & 63], red[0] + red[1] + red[2] + red[3]);
}

__global__ void finish(const double* __restrict__ s, float* __restrict__ out) {
  double v = s[threadIdx.x];
#pragma unroll
  for (int o = 32; o > 0; o >>= 1) v += __shfl_down(v, o);
  if (threadIdx.x == 0)
    out[0] = (float)(v * (1.0 / ((double)NN * (double)NN)));
}

extern "C" void kernel_launch(void* const* d_in, const int* in_sizes, int n_in,
                              void* d_out, int out_size, void* d_ws, size_t ws_size,
                              hipStream_t stream) {
  const float* y_inputs = (const float*)d_in[0];  // "inputs"
  const float* x_true   = (const float*)d_in[1];  // "true_samples"
  float* out = (float*)d_out;

  char* ws = (char*)d_ws;
  double* sums = (double*)ws;                     // 64 fp64 partial slots
  float* normZ = (float*)(ws + WS_NORM);
  __hip_bfloat16* Z = (__hip_bfloat16*)(ws + WS_Z);

  prep<<<TZ / 4, 256, 0, stream>>>(x_true, y_inputs, Z, normZ, sums);
  mmd_mfma<<<NBLOCKS, 256, 0, stream>>>(Z, normZ, sums);
  finish<<<1, 64, 0, stream>>>(sums, out);
}